// Round 1
// baseline (298.926 us; speedup 1.0000x reference)
//
#include <hip/hip_runtime.h>

// Problem constants (reference: B=32, N=1024, D=384, max_len=4096)
#define BB 32
#define NN 1024
#define DD 384
#define ML 4096
#define D4 (DD / 4)      // 96 float4 per row
#define ROWS 4           // output rows per block in gather kernel
#define GT (ROWS * D4)   // 384 threads per gather block

// Kernel 1: per-batch inclusive cumsum of durations -> cum[b][n] in ws.
__global__ __launch_bounds__(NN) void lr_cumsum_kernel(
    const int* __restrict__ dur, int* __restrict__ cum) {
    __shared__ int s[NN];
    const int b = blockIdx.x;
    const int i = threadIdx.x;
    s[i] = dur[b * NN + i];
    __syncthreads();
    // Hillis-Steele inclusive scan over 1024 elements
    #pragma unroll
    for (int off = 1; off < NN; off <<= 1) {
        int v = (i >= off) ? s[i - off] : 0;
        __syncthreads();
        s[i] += v;
        __syncthreads();
    }
    cum[b * NN + i] = s[i];
}

// Kernel 2: fused searchsorted(side='right') + gather + mask.
// Each block: ROWS output rows. Threads 0..ROWS-1 binary-search cum for
// their row's t, write mask float; then all GT threads copy float4s.
__global__ __launch_bounds__(GT) void lr_gather_kernel(
    const float4* __restrict__ x, const int* __restrict__ cum,
    float4* __restrict__ out, float* __restrict__ mask) {
    __shared__ int sidx[ROWS];
    const int tid  = threadIdx.x;
    const int row0 = blockIdx.x * ROWS;

    if (tid < ROWS) {
        const int row = row0 + tid;
        const int b = row >> 12;          // / ML
        const int t = row & (ML - 1);     // % ML
        const int* __restrict__ c = cum + (b << 10);  // * NN
        const int total = c[NN - 1];
        int pidx;
        if (t >= total) {
            pidx = -1;                    // masked -> zero row
        } else {
            // first index where c[i] > t  (searchsorted side='right')
            int lo = 0, hi = NN;
            while (lo < hi) {
                const int mid = (lo + hi) >> 1;
                if (c[mid] > t) hi = mid; else lo = mid + 1;
            }
            pidx = lo;                    // guaranteed < NN since t < total
        }
        sidx[tid] = pidx;
        mask[row] = (pidx < 0) ? 1.0f : 0.0f;
    }
    __syncthreads();

    const int r   = tid / D4;             // local row 0..ROWS-1
    const int d4  = tid - r * D4;         // float4 index within row
    const int row = row0 + r;
    const int pidx = sidx[r];
    float4 v = {0.0f, 0.0f, 0.0f, 0.0f};
    if (pidx >= 0) {
        const int b = row >> 12;
        v = x[((b << 10) + pidx) * D4 + d4];
    }
    out[row * D4 + d4] = v;
}

extern "C" void kernel_launch(void* const* d_in, const int* in_sizes, int n_in,
                              void* d_out, int out_size, void* d_ws, size_t ws_size,
                              hipStream_t stream) {
    const float* x  = (const float*)d_in[0];
    const int* dur  = (const int*)d_in[1];
    // d_in[2] is max_len scalar on device; fixed at 4096 per problem instance.

    int* cum    = (int*)d_ws;                       // B*N ints = 128 KB scratch
    float* out  = (float*)d_out;                    // (B, ML, D) fp32
    float* mask = out + (size_t)BB * ML * DD;       // (B, ML) as fp32 0/1

    lr_cumsum_kernel<<<BB, NN, 0, stream>>>(dur, cum);
    lr_gather_kernel<<<(BB * ML) / ROWS, GT, 0, stream>>>(
        (const float4*)x, cum, (float4*)out, mask);
}

// Round 2
// 244.739 us; speedup vs baseline: 1.2214x; 1.2214x over previous
//
#include <hip/hip_runtime.h>

// Problem constants (reference: B=32, N=1024, D=384, max_len=4096)
#define BB 32
#define NN 1024
#define DD 384
#define ML 4096
#define D4 (DD / 4)        // 96 float4 per row
#define RPB 8              // output rows per gather block
#define GT2 256            // gather block threads: 8 rows * 96 f4 = 768 = 3/thread
#define NBLK2 (BB * ML / RPB)  // 16384 gather blocks

// Kernel 1: per-batch scan of durations + scatter-inverse of searchsorted.
// Produces idx[b][t] (x-row index, -1 if t >= total) and mask[b][t].
__global__ __launch_bounds__(NN) void lr_scan_scatter_kernel(
    const int* __restrict__ dur, int* __restrict__ idxb,
    float* __restrict__ mask) {
    __shared__ int s[NN];
    __shared__ int idx_lds[ML];
    const int b = blockIdx.x;
    const int i = threadIdx.x;

    s[i] = dur[b * NN + i];
    #pragma unroll
    for (int k = 0; k < ML / NN; ++k) idx_lds[i + k * NN] = -1;
    __syncthreads();

    // Hillis-Steele inclusive scan over 1024 elements
    #pragma unroll
    for (int off = 1; off < NN; off <<= 1) {
        int v = (i >= off) ? s[i - off] : 0;
        __syncthreads();
        s[i] += v;
        __syncthreads();
    }

    // x-row i owns t in [cum[i-1], cum[i]); clamp to ML (totals can exceed it)
    const int end_raw = s[i];
    const int start   = (i == 0) ? 0 : s[i - 1];
    const int end     = (end_raw < ML) ? end_raw : ML;
    for (int t = start; t < end; ++t) idx_lds[t] = i;
    __syncthreads();

    #pragma unroll
    for (int k = 0; k < ML / NN; ++k) {
        const int t = i + k * NN;
        const int v = idx_lds[t];
        idxb[b * ML + t] = v;
        mask[b * ML + t] = (v < 0) ? 1.0f : 0.0f;
    }
}

// Kernel 2: pure streaming gather-copy. No barriers, no divergent search.
// Each block: RPB rows; thread does 3 float4 (768 f4 per block).
__global__ __launch_bounds__(GT2) void lr_copy_kernel(
    const float4* __restrict__ x, const int* __restrict__ idxb,
    float4* __restrict__ out) {
    // XCD-aware swizzle: give each XCD a contiguous run of rows so its
    // private L2 sees a small, reused slice of x (perf heuristic only).
    const int g = ((blockIdx.x & 7) * (NBLK2 / 8)) + (blockIdx.x >> 3);
    const int row0 = g * RPB;
    const int tid = threadIdx.x;

    #pragma unroll
    for (int k = 0; k < 3; ++k) {
        const int pos = tid + k * GT2;     // 0..767
        const int r   = pos / D4;          // const-div -> magic mul
        const int d4  = pos - r * D4;
        const int row = row0 + r;
        const int idx = idxb[row];         // L1-broadcast across the row's lanes
        float4 v = {0.0f, 0.0f, 0.0f, 0.0f};
        if (idx >= 0) {
            const int b = row >> 12;       // row / ML
            v = x[((b << 10) + idx) * D4 + d4];
        }
        out[(size_t)row * D4 + d4] = v;
    }
}

extern "C" void kernel_launch(void* const* d_in, const int* in_sizes, int n_in,
                              void* d_out, int out_size, void* d_ws, size_t ws_size,
                              hipStream_t stream) {
    const float* x = (const float*)d_in[0];
    const int* dur = (const int*)d_in[1];
    // d_in[2] is max_len scalar; fixed at 4096 for this problem instance.

    int* idxb   = (int*)d_ws;                      // B*ML ints = 512 KB scratch
    float* out  = (float*)d_out;                   // (B, ML, D) fp32
    float* mask = out + (size_t)BB * ML * DD;      // (B, ML) as fp32 0/1

    lr_scan_scatter_kernel<<<BB, NN, 0, stream>>>(dur, idxb, mask);
    lr_copy_kernel<<<NBLK2, GT2, 0, stream>>>(
        (const float4*)x, idxb, (float4*)out);
}